// Round 13
// baseline (209.186 us; speedup 1.0000x reference)
//
#include <hip/hip_runtime.h>
#include <math.h>

#define D 128
#define EPSV 1e-5f

typedef unsigned short ushort_t;
typedef unsigned char uchar_t;
typedef __attribute__((ext_vector_type(8))) short short8v;
typedef __attribute__((ext_vector_type(4))) float f32x4;
typedef __attribute__((ext_vector_type(2))) float f32x2;
typedef _Float16 half_t;
typedef __attribute__((ext_vector_type(2))) _Float16 h2;

#if __has_builtin(__builtin_amdgcn_cvt_pk_f16_fp8)
#define HAVE_F16P 1
#else
#define HAVE_F16P 0
#endif

// q is pre-scaled by (1/sqrt(32)) * log2(e) so the edge kernel uses exp2f directly
#define QKS (0.17677669529663687f * 1.4426950408889634f)

__device__ __forceinline__ float bf2f(unsigned u) {
    return __uint_as_float(u << 16);
}
__device__ __forceinline__ ushort_t f2bf(float f) {
    unsigned u = __float_as_uint(f);
    unsigned r = (u + 0x7fffu + ((u >> 16) & 1u)) >> 16;   // RNE
    return (ushort_t)r;
}
__device__ __forceinline__ float bfp(uint4 v, int i) {   // bf16 element i of 8
    unsigned w = (&v.x)[i >> 1];
    return bf2f((i & 1) ? (w >> 16) : (w & 0xffffu));
}

// q storage format: f16 when the fast fp8->f16 path exists, else bf16
__device__ __forceinline__ ushort_t qconv(float f) {
#if HAVE_F16P
    half_t h = (half_t)f;
    return __builtin_bit_cast(ushort_t, h);
#else
    return f2bf(f);
#endif
}

// unpack 8 fp8 (e4m3, 8 bytes in 2 uints) -> 8 f32 via HW cvt (fallback path)
#define UNPACK8_FP8(ux, uy, o) { \
    f32x2 _a = __builtin_amdgcn_cvt_pk_f32_fp8((int)(ux), false); \
    f32x2 _b = __builtin_amdgcn_cvt_pk_f32_fp8((int)(ux), true);  \
    f32x2 _c = __builtin_amdgcn_cvt_pk_f32_fp8((int)(uy), false); \
    f32x2 _d = __builtin_amdgcn_cvt_pk_f32_fp8((int)(uy), true);  \
    o[0] = _a.x; o[1] = _a.y; o[2] = _b.x; o[3] = _b.y;           \
    o[4] = _c.x; o[5] = _c.y; o[6] = _d.x; o[7] = _d.y; }

// pack 4 bf16 (in uints w0=[e1|e0], w1=[e3|e2]) -> 4 fp8 in one uint
__device__ __forceinline__ unsigned bf4_to_fp8x4(unsigned w0, unsigned w1) {
    int u = __builtin_amdgcn_cvt_pk_fp8_f32(bf2f(w0 & 0xffffu), bf2f(w0 >> 16), 0, false);
    u = __builtin_amdgcn_cvt_pk_fp8_f32(bf2f(w1 & 0xffffu), bf2f(w1 >> 16), u, true);
    return (unsigned)u;
}

__device__ __forceinline__ h2 h2_shfl_xor_add(h2 a, int off) {
    return a + __builtin_bit_cast(h2, __shfl_xor(__builtin_bit_cast(int, a), off));
}

// ========== merged: x -> bf16 (streaming) + degree count (same grid) ==========
__global__ void cvt_deg_kernel(const float* __restrict__ in, ushort_t* __restrict__ out, int n8,
                               const int* __restrict__ dst, int* __restrict__ deg, int E)
{
    int i = blockIdx.x * blockDim.x + threadIdx.x;
    if (i < n8) {
        float4 a = reinterpret_cast<const float4*>(in)[i * 2];
        float4 b = reinterpret_cast<const float4*>(in)[i * 2 + 1];
        uint4 o;
        o.x = (unsigned)f2bf(a.x) | ((unsigned)f2bf(a.y) << 16);
        o.y = (unsigned)f2bf(a.z) | ((unsigned)f2bf(a.w) << 16);
        o.z = (unsigned)f2bf(b.x) | ((unsigned)f2bf(b.y) << 16);
        o.w = (unsigned)f2bf(b.z) | ((unsigned)f2bf(b.w) << 16);
        reinterpret_cast<uint4*>(out)[i] = o;
    }
    if (i < E) atomicAdd(&deg[dst[i]], 1);
}

// ============ projection GEMM: pack/q/xr = xbf @ wt_all, one col-tile per block ============
// grid (MB, 5). pack row [512 B, 384 used] fp8 = 16 x [k8|v8] (256 B) | xw*dinv (128 B).
__global__ __launch_bounds__(256)
void proj_gemm(const ushort_t* __restrict__ xbf,   // [M][128] bf16
               const ushort_t* __restrict__ Bt,    // wt_all [640][128]
               const float* __restrict__ bias,     // [640]
               const float* __restrict__ dinv,     // [M]
               uchar_t* __restrict__ pack, ushort_t* __restrict__ qb,
               ushort_t* __restrict__ xrb, int M)
{
    __shared__ ushort_t Cs[128 * 136];
    const int tid = threadIdx.x, lane = tid & 63, wid = tid >> 6;
    const int wr = wid >> 1, wc = wid & 1;
    const int R0 = blockIdx.x * 128;
    const int ct = blockIdx.y;

    short8v av[4][4];                         // [r][ks] bf16 A fragments
    #pragma unroll
    for (int r = 0; r < 4; ++r) {
        int gr = R0 + wr * 64 + r * 16 + (lane & 15);
        if (gr >= M) gr = M - 1;
        #pragma unroll
        for (int ks = 0; ks < 4; ++ks)
            av[r][ks] = *reinterpret_cast<const short8v*>(
                &xbf[(size_t)gr * 128 + ks * 32 + (lane >> 4) * 8]);
    }

    f32x4 acc[4][4] = {};
    #pragma unroll
    for (int ks = 0; ks < 4; ++ks) {
        short8v bv[4];
        #pragma unroll
        for (int c = 0; c < 4; ++c) {
            int col = ct * 128 + wc * 64 + c * 16 + (lane & 15);
            bv[c] = *reinterpret_cast<const short8v*>(
                &Bt[(size_t)col * 128 + ks * 32 + (lane >> 4) * 8]);
        }
        #pragma unroll
        for (int r = 0; r < 4; ++r)
            #pragma unroll
            for (int c = 0; c < 4; ++c)
                acc[r][c] = __builtin_amdgcn_mfma_f32_16x16x32_bf16(av[r][ks], bv[c], acc[r][c], 0, 0, 0);
    }

    #pragma unroll
    for (int r = 0; r < 4; ++r) {
        int rowb = wr * 64 + r * 16 + (lane >> 4) * 4;
        #pragma unroll
        for (int i = 0; i < 4; ++i) {
            float sc = 1.f;
            if (ct == 0) {
                int grow = R0 + rowb + i;
                if (grow >= M) grow = M - 1;
                sc = dinv[grow];              // pre-scale xw by dinv[src]
            }
            #pragma unroll
            for (int c = 0; c < 4; ++c) {
                int col = wc * 64 + c * 16 + (lane & 15);
                float val = acc[r][c][i] + bias[ct * 128 + col];
                if (ct == 0) val *= sc;
                if (ct == 1) val *= QKS;      // fold softmax scale + log2e into q
                Cs[(rowb + i) * 136 + col] = (ct == 1) ? qconv(val) : f2bf(val);
            }
        }
    }
    __syncthreads();

    if (ct == 1 || ct == 4) {                 // 16-bit outputs: q, x_r
        #pragma unroll
        for (int it = 0; it < 8; ++it) {      // 128 rows x 16 chunks of 16B
            int linear = tid + it * 256;
            int row = linear >> 4, ch = linear & 15;
            int gr = R0 + row;
            if (gr < M) {
                uint4 v = *reinterpret_cast<const uint4*>(&Cs[row * 136 + ch * 8]);
                ushort_t* dst = (ct == 1) ? (qb + (size_t)gr * 128)
                                          : (xrb + (size_t)gr * 128);
                *reinterpret_cast<uint4*>(dst + ch * 8) = v;
            }
        }
    } else {                                  // fp8 outputs: xw(ct0), k(ct2), v(ct3)
        #pragma unroll
        for (int it = 0; it < 4; ++it) {      // 128 rows x 8 chunks of 16 fp8
            int linear = tid + it * 256;
            int row = linear >> 3, ch = linear & 7;
            int gr = R0 + row;
            if (gr < M) {
                uint4 lo = *reinterpret_cast<const uint4*>(&Cs[row * 136 + ch * 16]);
                uint4 hi = *reinterpret_cast<const uint4*>(&Cs[row * 136 + ch * 16 + 8]);
                uint4 o;
                o.x = bf4_to_fp8x4(lo.x, lo.y);
                o.y = bf4_to_fp8x4(lo.z, lo.w);
                o.z = bf4_to_fp8x4(hi.x, hi.y);
                o.w = bf4_to_fp8x4(hi.z, hi.w);
                uchar_t* prow = pack + ((size_t)gr << 9);
                if (ct == 0) {                // xw: contiguous at 256 + ch*16
                    *reinterpret_cast<uint4*>(prow + 256 + ch * 16) = o;
                } else if (ct == 2) {         // k: groups 2ch, 2ch+1, offset 0
                    *reinterpret_cast<uint2*>(prow + (2 * ch) * 16)     = make_uint2(o.x, o.y);
                    *reinterpret_cast<uint2*>(prow + (2 * ch + 1) * 16) = make_uint2(o.z, o.w);
                } else {                      // v: groups 2ch, 2ch+1, offset 8
                    *reinterpret_cast<uint2*>(prow + (2 * ch) * 16 + 8)     = make_uint2(o.x, o.y);
                    *reinterpret_cast<uint2*>(prow + (2 * ch + 1) * 16 + 8) = make_uint2(o.z, o.w);
                }
            }
        }
    }
}

// ============ fused FFN1 + FFN2 + residual + LayerNorm2 -> f32 out ============
__device__ __forceinline__ int swz(int ch, int row) {
    return (ch & 24) | ((ch ^ row) & 7);
}

__global__ __launch_bounds__(256)
void ffn_fused(const ushort_t* __restrict__ hlnb,     // [M][128] bf16
               const ushort_t* __restrict__ wt_rel,   // [256][128] bf16
               const ushort_t* __restrict__ wt_root,  // [128][256] bf16
               const float* __restrict__ g2, const float* __restrict__ b2,
               float* __restrict__ outf, int M)
{
    __shared__ float smem[128 * 130];                 // 66.6 KB
    ushort_t* Hs = (ushort_t*)smem;                   // hidden bf16 [128][256] swizzled
    const int tid = threadIdx.x, lane = tid & 63, wid = tid >> 6;
    const int wr = wid >> 1, wc = wid & 1;
    const int R0 = blockIdx.x * 128;

    short8v av[4][4];
    #pragma unroll
    for (int r = 0; r < 4; ++r) {
        int gr = R0 + wr * 64 + r * 16 + (lane & 15);
        if (gr >= M) gr = M - 1;
        #pragma unroll
        for (int ks = 0; ks < 4; ++ks)
            av[r][ks] = *reinterpret_cast<const short8v*>(
                &hlnb[(size_t)gr * 128 + ks * 32 + (lane >> 4) * 8]);
    }
    for (int ct = 0; ct < 2; ++ct) {
        f32x4 acc[4][4] = {};
        #pragma unroll
        for (int ks = 0; ks < 4; ++ks) {
            short8v bv[4];
            #pragma unroll
            for (int c = 0; c < 4; ++c) {
                int col = ct * 128 + wc * 64 + c * 16 + (lane & 15);
                bv[c] = *reinterpret_cast<const short8v*>(
                    &wt_rel[(size_t)col * 128 + ks * 32 + (lane >> 4) * 8]);
            }
            #pragma unroll
            for (int r = 0; r < 4; ++r)
                #pragma unroll
                for (int c = 0; c < 4; ++c)
                    acc[r][c] = __builtin_amdgcn_mfma_f32_16x16x32_bf16(av[r][ks], bv[c], acc[r][c], 0, 0, 0);
        }
        #pragma unroll
        for (int r = 0; r < 4; ++r) {
            int rowb = wr * 64 + r * 16 + (lane >> 4) * 4;
            #pragma unroll
            for (int i = 0; i < 4; ++i)
                #pragma unroll
                for (int c = 0; c < 4; ++c) {
                    int row = rowb + i;
                    int col = ct * 128 + wc * 64 + c * 16 + (lane & 15);
                    int ch = col >> 3, el = col & 7;
                    Hs[row * 256 + swz(ch, row) * 8 + el] = f2bf(fmaxf(acc[r][c][i], 0.f));
                }
        }
    }
    __syncthreads();

    f32x4 acc2[4][4] = {};
    #pragma unroll
    for (int ks = 0; ks < 8; ++ks) {
        short8v a2[4], bv[4];
        #pragma unroll
        for (int r = 0; r < 4; ++r) {
            int row = wr * 64 + r * 16 + (lane & 15);
            int ch = ks * 4 + (lane >> 4);
            a2[r] = *reinterpret_cast<const short8v*>(&Hs[row * 256 + swz(ch, row) * 8]);
        }
        #pragma unroll
        for (int c = 0; c < 4; ++c) {
            int col = wc * 64 + c * 16 + (lane & 15);
            bv[c] = *reinterpret_cast<const short8v*>(
                &wt_root[(size_t)col * 256 + ks * 32 + (lane >> 4) * 8]);
        }
        #pragma unroll
        for (int r = 0; r < 4; ++r)
            #pragma unroll
            for (int c = 0; c < 4; ++c)
                acc2[r][c] = __builtin_amdgcn_mfma_f32_16x16x32_bf16(a2[r], bv[c], acc2[r][c], 0, 0, 0);
    }
    __syncthreads();                          // hidden reads done; reuse as f32 C

    float* Cs = smem;                         // [128][130]
    #pragma unroll
    for (int r = 0; r < 4; ++r) {
        int rowb = wr * 64 + r * 16 + (lane >> 4) * 4;
        #pragma unroll
        for (int i = 0; i < 4; ++i)
            #pragma unroll
            for (int c = 0; c < 4; ++c)
                Cs[(rowb + i) * 130 + wc * 64 + c * 16 + (lane & 15)] = acc2[r][c][i];
    }
    __syncthreads();

    const float ga = g2[lane * 2], gb = g2[lane * 2 + 1];
    const float ba = b2[lane * 2], bb2 = b2[lane * 2 + 1];
    for (int rr = 0; rr < 32; ++rr) {
        int row = wid * 32 + rr;
        int gr = R0 + row;
        if (gr >= M) break;
        unsigned hu = *reinterpret_cast<const unsigned*>(&hlnb[(size_t)gr * 128 + lane * 2]);
        float t0 = Cs[row * 130 + lane * 2]     + bf2f(hu & 0xffffu);
        float t1 = Cs[row * 130 + lane * 2 + 1] + bf2f(hu >> 16);
        float ssum = t0 + t1;
        #pragma unroll
        for (int off = 1; off <= 32; off <<= 1) ssum += __shfl_xor(ssum, off);
        float mu = ssum * (1.f / 128.f);
        float dv0 = t0 - mu, dv1 = t1 - mu;
        float vsum = dv0 * dv0 + dv1 * dv1;
        #pragma unroll
        for (int off = 1; off <= 32; off <<= 1) vsum += __shfl_xor(vsum, off);
        float rs = rsqrtf(vsum * (1.f / 128.f) + EPSV);
        float2 o = make_float2(dv0 * rs * ga + ba, dv1 * rs * gb + bb2);
        *reinterpret_cast<float2*>(&outf[(size_t)gr * 128 + lane * 2]) = o;
    }
}

// =============== merged: padded scan1 (blocks < SB) + weight packing (blocks >= SB) ===============
// scans pdeg = (deg+3)&~3 so every node's edge range is a multiple of 4
__global__ __launch_bounds__(256)
void scan1_packw_kernel(const int* __restrict__ deg, int* __restrict__ row_start,
                        int* __restrict__ bsum, int n, int SB,
                        const float* __restrict__ wg, const float* __restrict__ wq,
                        const float* __restrict__ wk, const float* __restrict__ wv,
                        const float* __restrict__ wsk,
                        const float* __restrict__ bq, const float* __restrict__ bk,
                        const float* __restrict__ bv, const float* __restrict__ bsk,
                        const float* __restrict__ wrel, const float* __restrict__ wroot,
                        ushort_t* __restrict__ wt_all, ushort_t* __restrict__ wt_rel,
                        ushort_t* __restrict__ wt_root, float* __restrict__ bias_all)
{
    __shared__ int ws[4];
    if ((int)blockIdx.x < SB) {
        const int t = threadIdx.x, lane = t & 63, wid = t >> 6;
        const int base = blockIdx.x * 1024 + t * 4;
        int v0 = 0, v1 = 0, v2 = 0, v3 = 0;
        if (base + 3 < n) {
            int4 q = *reinterpret_cast<const int4*>(&deg[base]);
            v0 = q.x; v1 = q.y; v2 = q.z; v3 = q.w;
        } else {
            if (base < n)     v0 = deg[base];
            if (base + 1 < n) v1 = deg[base + 1];
            if (base + 2 < n) v2 = deg[base + 2];
            if (base + 3 < n) v3 = deg[base + 3];
        }
        int p0 = (v0 + 3) & ~3, p1 = (v1 + 3) & ~3;
        int p2 = (v2 + 3) & ~3, p3 = (v3 + 3) & ~3;
        int tot = p0 + p1 + p2 + p3;
        int inc = tot;
        #pragma unroll
        for (int off = 1; off < 64; off <<= 1) {
            int y = __shfl_up(inc, off);
            if (lane >= off) inc += y;
        }
        if (lane == 63) ws[wid] = inc;
        __syncthreads();
        int woff = 0;
        for (int w = 0; w < wid; ++w) woff += ws[w];
        int excl = woff + inc - tot;
        if (base < n)     row_start[base]     = excl;
        if (base + 1 < n) row_start[base + 1] = excl + p0;
        if (base + 2 < n) row_start[base + 2] = excl + p0 + p1;
        if (base + 3 < n) row_start[base + 3] = excl + p0 + p1 + p2;
        if (t == 0) bsum[blockIdx.x] = ws[0] + ws[1] + ws[2] + ws[3];
    } else {
        int i = (blockIdx.x - SB) * 256 + threadIdx.x;
        if (i < 640 * 128) {                         // wt_all[n][k] = W[k][n]
            int c = i >> 7, k = i & 127;
            const float* srcs[5] = {wg, wq, wk, wv, wsk};
            wt_all[i] = f2bf(srcs[c >> 7][k * 128 + (c & 127)]);
        } else if (i < 640 * 128 + 256 * 128) {
            int j = i - 640 * 128;
            int c = j >> 7, k = j & 127;
            wt_rel[j] = f2bf(wrel[k * 256 + c]);
        } else if (i < 640 * 128 + 256 * 128 + 128 * 256) {
            int j = i - (640 * 128 + 256 * 128);
            int c = j >> 8, k = j & 255;
            wt_root[j] = f2bf(wroot[k * 128 + c]);
        } else if (i < 640 * 128 + 256 * 128 + 128 * 256 + 640) {
            int c = i - (640 * 128 + 256 * 128 + 128 * 256);
            float b = 0.f;
            if (c >= 128) {
                const float* bs[4] = {bq, bk, bv, bsk};
                b = bs[(c - 128) >> 7][c & 127];
            }
            bias_all[c] = b;
        }
    }
}

// apply block offsets (prefix via parallel wave reduce); derive cursor, dinv, row_start[n]
__global__ __launch_bounds__(256)
void scan3_kernel(const int* __restrict__ deg, const int* __restrict__ bsum,
                  int* __restrict__ row_start, int* __restrict__ cursor,
                  float* __restrict__ dinv, int n)
{
    __shared__ int boff_s;
    const int K = blockIdx.x >> 2;          // # of 1024-chunks before this block's chunk
    const int t = threadIdx.x;
    if (t < 64) {                           // parallel sum of bsum[0..K-1]
        int v = 0;
        for (int j = t; j < K; j += 64) v += bsum[j];
        #pragma unroll
        for (int off = 1; off <= 32; off <<= 1) v += __shfl_xor(v, off);
        if (t == 0) boff_s = v;
    }
    __syncthreads();
    int i = blockIdx.x * 256 + t;
    if (i < n) {
        int rs = row_start[i] + boff_s;
        row_start[i] = rs;
        cursor[i] = rs;
        int d = deg[i];
        dinv[i] = (d > 0) ? rsqrtf((float)d) : 0.f;
        if (i == n - 1) row_start[n] = rs + ((d + 3) & ~3);
    }
}

// edges part (t < EH): scatter real edges; node part: write pad entries = n
__global__ void fill_kernel(const int* __restrict__ src, const int* __restrict__ dst,
                            int* __restrict__ cursor, int* __restrict__ csr_src,
                            const int* __restrict__ row_start, const int* __restrict__ deg,
                            int E, int EH, int n)
{
    int t = blockIdx.x * blockDim.x + threadIdx.x;
    if (t < EH) {
        int e = t * 2;
        if (e + 1 < E) {
            int2 s2 = *reinterpret_cast<const int2*>(&src[e]);
            int2 d2 = *reinterpret_cast<const int2*>(&dst[e]);
            int p0 = atomicAdd(&cursor[d2.x], 1);
            csr_src[p0] = s2.x;
            int p1 = atomicAdd(&cursor[d2.y], 1);
            csr_src[p1] = s2.y;
        } else if (e < E) {
            int d = dst[e];
            int pos = atomicAdd(&cursor[d], 1);
            csr_src[pos] = src[e];
        }
    } else {
        int i = t - EH;
        if (i < n) {
            int rs = row_start[i], d = deg[i];
            int pd = (d + 3) & ~3;
            for (int j = rs + d; j < rs + pd; ++j) csr_src[j] = n;
        }
    }
}

// ===== fused: GCN gather + attention + beta gate + combine + LayerNorm1 =====
// pack row [512 B]: 16 x [k8|v8] (256) | xw*dinv (128) | pad; row n zeroed.
// Padded CSR: every range is a multiple of 4; pads point at zero row (wgt=exp2(0)=1,
// subtracted exactly via pdeg-deg). q pre-scaled by QKS -> wgt = exp2f(p).
__global__ __launch_bounds__(256)
void edge_fused_kernel(const uchar_t* __restrict__ pack,
                       const ushort_t* __restrict__ qbf,
                       const ushort_t* __restrict__ xrbf,
                       const int* __restrict__ row_start,
                       const int* __restrict__ csr_src,
                       const int* __restrict__ degp,
                       const float* __restrict__ dinv,
                       const float* __restrict__ b_gcn,
                       const float* __restrict__ w_beta,
                       const float* __restrict__ g1, const float* __restrict__ b1,
                       const float* __restrict__ local_w, const float* __restrict__ global_w,
                       ushort_t* __restrict__ hln_bf, int n)
{
    const int wid = threadIdx.x >> 6, lane = threadIdx.x & 63;
    const int node = blockIdx.x * 4 + wid;
    if (node >= n) return;
    const int slot = lane >> 4, li = lane & 15;
    const int d8 = li * 8;

    const int e0 = row_start[node], e1 = row_start[node + 1];
    const int cnt = degp[node];              // true degree
    const float dn = dinv[node];

    float s = 0.f;
    float va[8], ga[8];

#if HAVE_F16P
    // ---- f16 packed-math path (q stored as f16, pre-scaled) ----
    uint4 qu = *reinterpret_cast<const uint4*>(&qbf[(size_t)node * 128 + d8]);
    h2 qh[4] = { __builtin_bit_cast(h2, qu.x), __builtin_bit_cast(h2, qu.y),
                 __builtin_bit_cast(h2, qu.z), __builtin_bit_cast(h2, qu.w) };
    h2 va2[4] = {}, ga2[4] = {};
    for (int j = e0; j < e1; j += 4) {
        const int sidx = csr_src[j + slot];           // pads -> row n (zeros)
        const uchar_t* prow = pack + ((size_t)sidx << 9);
        uint4 kv = *reinterpret_cast<const uint4*>(prow + li * 16);       // k8|v8
        uint2 xu = *reinterpret_cast<const uint2*>(prow + 256 + li * 8);  // xw8
        h2 k0 = __builtin_amdgcn_cvt_pk_f16_fp8((short)(kv.x & 0xffffu));
        h2 k1 = __builtin_amdgcn_cvt_pk_f16_fp8((short)(kv.x >> 16));
        h2 k2 = __builtin_amdgcn_cvt_pk_f16_fp8((short)(kv.y & 0xffffu));
        h2 k3 = __builtin_amdgcn_cvt_pk_f16_fp8((short)(kv.y >> 16));
        float p = __builtin_amdgcn_fdot2(k0, qh[0], 0.f, false);
        p = __builtin_amdgcn_fdot2(k1, qh[1], p, false);
        p = __builtin_amdgcn_fdot2(k2, qh[2], p, false);
        p = __builtin_amdgcn_fdot2(k3, qh[3], p, false);
        p += __shfl_xor(p, 1);                        // head = li>>2 : 4-lane groups
        p += __shfl_xor(p, 2);
        float wgt = exp2f(p);                         // q pre-scaled; pad: exp2(0)=1
        s += wgt;
        half_t wh = (half_t)wgt;
        h2 w2 = { wh, wh };
        h2 v0 = __builtin_amdgcn_cvt_pk_f16_fp8((short)(kv.z & 0xffffu));
        h2 v1 = __builtin_amdgcn_cvt_pk_f16_fp8((short)(kv.z >> 16));
        h2 v2 = __builtin_amdgcn_cvt_pk_f16_fp8((short)(kv.w & 0xffffu));
        h2 v3 = __builtin_amdgcn_cvt_pk_f16_fp8((short)(kv.w >> 16));
        va2[0] += w2 * v0; va2[1] += w2 * v1; va2[2] += w2 * v2; va2[3] += w2 * v3;
        h2 x0 = __builtin_amdgcn_cvt_pk_f16_fp8((short)(xu.x & 0xffffu));
        h2 x1 = __builtin_amdgcn_cvt_pk_f16_fp8((short)(xu.x >> 16));
        h2 x2 = __builtin_amdgcn_cvt_pk_f16_fp8((short)(xu.y & 0xffffu));
        h2 x3 = __builtin_amdgcn_cvt_pk_f16_fp8((short)(xu.y >> 16));
        ga2[0] += x0; ga2[1] += x1; ga2[2] += x2; ga2[3] += x3;
    }
    // slot-combine in f16 (8 h2 regs x 2 stages = 16 shfl)
    #pragma unroll
    for (int off = 16; off <= 32; off <<= 1) {
        #pragma unroll
        for (int i = 0; i < 4; ++i) {
            va2[i] = h2_shfl_xor_add(va2[i], off);
            ga2[i] = h2_shfl_xor_add(ga2[i], off);
        }
    }
    #pragma unroll
    for (int i = 0; i < 4; ++i) {
        va[2 * i] = (float)va2[i][0]; va[2 * i + 1] = (float)va2[i][1];
        ga[2 * i] = (float)ga2[i][0]; ga[2 * i + 1] = (float)ga2[i][1];
    }
#else
    // ---- fallback f32 path (q stored as bf16, pre-scaled) ----
    uint4 qu = *reinterpret_cast<const uint4*>(&qbf[(size_t)node * 128 + d8]);
    float q[8];
    #pragma unroll
    for (int i = 0; i < 8; ++i) q[i] = bfp(qu, i);
    #pragma unroll
    for (int i = 0; i < 8; ++i) { va[i] = 0.f; ga[i] = 0.f; }
    for (int j = e0; j < e1; j += 4) {
        const int sidx = csr_src[j + slot];
        const uchar_t* prow = pack + ((size_t)sidx << 9);
        uint4 kv = *reinterpret_cast<const uint4*>(prow + li * 16);
        uint2 xu = *reinterpret_cast<const uint2*>(prow + 256 + li * 8);
        float kf[8], vf[8], xf[8];
        UNPACK8_FP8(kv.x, kv.y, kf);
        UNPACK8_FP8(kv.z, kv.w, vf);
        UNPACK8_FP8(xu.x, xu.y, xf);
        float p = 0.f;
        #pragma unroll
        for (int i = 0; i < 8; ++i) p = fmaf(q[i], kf[i], p);
        p += __shfl_xor(p, 1);
        p += __shfl_xor(p, 2);
        float wgt = exp2f(p);
        s += wgt;
        #pragma unroll
        for (int i = 0; i < 8; ++i) {
            va[i] = fmaf(wgt, vf[i], va[i]);
            ga[i] += xf[i];
        }
    }
    #pragma unroll
    for (int off = 16; off <= 32; off <<= 1) {
        #pragma unroll
        for (int i = 0; i < 8; ++i) {
            va[i] += __shfl_xor(va[i], off);
            ga[i] += __shfl_xor(ga[i], off);
        }
    }
#endif

    // s combine + pad correction (each pad entry added exp2(0)=1 to every head)
    s += __shfl_xor(s, 16);
    s += __shfl_xor(s, 32);
    s -= (float)((e1 - e0) - cnt);
    const float denom = fmaxf(s, 1e-16f);        // per-head (head = li>>2)

    uint4 xru = *reinterpret_cast<const uint4*>(&xrbf[(size_t)node * 128 + d8]);
    float t[8];
    float part = 0.f;
    #pragma unroll
    for (int i = 0; i < 8; ++i) {
        float og = va[i] / denom;
        float xr = bfp(xru, i);
        float lo = dn * ga[i] + b_gcn[d8 + i];   // dn applied post-loop (xw pre-scaled)
        part += og * w_beta[d8 + i] + xr * w_beta[128 + d8 + i]
              + (og - xr) * w_beta[256 + d8 + i];
        t[i] = lo;
        va[i] = og; ga[i] = xr;                   // reuse regs: va=og, ga=xr
    }
    // 16-lane reductions (slot groups are exact duplicates)
    #pragma unroll
    for (int off = 1; off <= 8; off <<= 1) part += __shfl_xor(part, off);
    const float beta = 1.f / (1.f + __expf(-part));

    const float lw = local_w[0], gw = global_w[0];
    float ssum = 0.f;
    #pragma unroll
    for (int i = 0; i < 8; ++i) {
        float go = beta * ga[i] + (1.f - beta) * va[i];
        t[i] = 2.f * (lw * t[i] + gw * go);
        ssum += t[i];
    }
    #pragma unroll
    for (int off = 1; off <= 8; off <<= 1) ssum += __shfl_xor(ssum, off);
    const float mu = ssum * (1.f / 128.f);
    float vsum = 0.f;
    #pragma unroll
    for (int i = 0; i < 8; ++i) { float d = t[i] - mu; vsum += d * d; }
    #pragma unroll
    for (int off = 1; off <= 8; off <<= 1) vsum += __shfl_xor(vsum, off);
    const float rs = rsqrtf(vsum * (1.f / 128.f) + EPSV);

    if (slot == 0) {
        uint4 o;
        #pragma unroll
        for (int i = 0; i < 4; ++i) {
            float o0 = (t[2*i]   - mu) * rs * g1[d8 + 2*i]   + b1[d8 + 2*i];
            float o1 = (t[2*i+1] - mu) * rs * g1[d8 + 2*i+1] + b1[d8 + 2*i+1];
            (&o.x)[i] = (unsigned)f2bf(o0) | ((unsigned)f2bf(o1) << 16);
        }
        *reinterpret_cast<uint4*>(&hln_bf[(size_t)node * 128 + d8]) = o;
    }
}

// =================== launch ===================
extern "C" void kernel_launch(void* const* d_in, const int* in_sizes, int n_in,
                              void* d_out, int out_size, void* d_ws, size_t ws_size,
                              hipStream_t stream)
{
    const float* x      = (const float*)d_in[0];
    const int*   ei     = (const int*)d_in[1];
    const float* w_gcn  = (const float*)d_in[2];
    const float* b_gcn  = (const float*)d_in[3];
    const float* wq     = (const float*)d_in[4];
    const float* bq     = (const float*)d_in[5];
    const float* wk     = (const float*)d_in[6];
    const float* bk     = (const float*)d_in[7];
    const float* wv     = (const float*)d_in[8];
    const float* bv     = (const float*)d_in[9];
    const float* w_skip = (const float*)d_in[10];
    const float* b_skip = (const float*)d_in[11];
    const float* w_beta = (const float*)d_in[12];
    const float* g1     = (const float*)d_in[13];
    const float* b1     = (const float*)d_in[14];
    const float* g2     = (const float*)d_in[15];
    const float* b2     = (const float*)d_in[16];
    const float* w_rel  = (const float*)d_in[17];
    const float* w_root = (const float*)d_in[18];
    const float* lw     = (const float*)d_in[19];
    const float* gw     = (const float*)d_in[20];

    const int N = in_sizes[0] / D;
    const int E = in_sizes[1] / 2;
    const int* src = ei;
    const int* dst = ei + E;

    char* wsb = (char*)d_ws;
    size_t off = 0;
    auto alloc = [&](size_t bytes) -> void* {
        void* p = wsb + off;
        off += (bytes + 255) & ~(size_t)255;
        return p;
    };
    uchar_t*  pack_kvx = (uchar_t*)alloc((size_t)(N + 1) * 512);   // [k8|v8]x16 | xw | pad
    ushort_t* xbf      = (ushort_t*)alloc((size_t)N * 128 * 2);
    ushort_t* qb_bf    = (ushort_t*)alloc((size_t)N * 128 * 2);
    ushort_t* xr_bf    = (ushort_t*)alloc((size_t)N * 128 * 2);
    ushort_t* hln_bf   = (ushort_t*)alloc((size_t)N * 128 * 2);
    ushort_t* wt_all   = (ushort_t*)alloc(640 * 128 * 2);
    ushort_t* wt_rel   = (ushort_t*)alloc(256 * 128 * 2);
    ushort_t* wt_root  = (ushort_t*)alloc(128 * 256 * 2);
    float*    bias_all = (float*)alloc(640 * 4);
    int*      deg      = (int*)alloc((size_t)N * 4);
    int*      row_start= (int*)alloc((size_t)(N + 1) * 4);
    int*      cursor   = (int*)alloc((size_t)N * 4);
    int*      csr_src  = (int*)alloc((size_t)(E + 3 * (size_t)N + 4) * 4);  // padded CSR
    float*    dinv     = (float*)alloc((size_t)N * 4);
    int*      bsum     = (int*)alloc(((size_t)(N + 1023) / 1024) * 4);

    float* out = (float*)d_out;
    const int SB = (N + 1023) / 1024;
    const int n8 = N * 16;                    // uint4 chunks for cvt
    const int EH = (E + 1) / 2;

    // ---- graph prep (+ weight packing merged into scan1 launch) ----
    hipMemsetAsync(deg, 0, (size_t)N * sizeof(int), stream);
    hipMemsetAsync(pack_kvx + (size_t)N * 512, 0, 512, stream);    // zero dummy row
    {
        int work = (n8 > E) ? n8 : E;
        cvt_deg_kernel<<<dim3((work + 255) / 256), dim3(256), 0, stream>>>(
            x, xbf, n8, dst, deg, E);
    }
    scan1_packw_kernel<<<dim3(SB + 579), dim3(256), 0, stream>>>(
        deg, row_start, bsum, N, SB,
        w_gcn, wq, wk, wv, w_skip, bq, bk, bv, b_skip, w_rel, w_root,
        wt_all, wt_rel, wt_root, bias_all);
    scan3_kernel<<<dim3((N + 255) / 256), dim3(256), 0, stream>>>(
        deg, bsum, row_start, cursor, dinv, N);
    fill_kernel<<<dim3((EH + N + 255) / 256), dim3(256), 0, stream>>>(
        src, dst, cursor, csr_src, row_start, deg, E, EH, N);

    // ---- fused projections: one col-tile per block, bf16 A ----
    const int MB = (N + 127) / 128;
    proj_gemm<<<dim3(MB, 5), dim3(256), 0, stream>>>(
        xbf, wt_all, bias_all, dinv, pack_kvx, qb_bf, xr_bf, N);

    // ---- fused edge phase (fp8 gathers, f16 packed math, padded CSR) ----
    edge_fused_kernel<<<dim3((N + 3) / 4), dim3(256), 0, stream>>>(
        pack_kvx, qb_bf, xr_bf, row_start, csr_src, deg, dinv, b_gcn, w_beta,
        g1, b1, lw, gw, hln_bf, N);

    // ---- fused FFN + LN2 ----
    ffn_fused<<<dim3(MB), dim3(256), 0, stream>>>(
        hln_bf, wt_rel, wt_root, g2, b2, out, N);
}

// Round 14
// 205.534 us; speedup vs baseline: 1.0178x; 1.0178x over previous
//
#include <hip/hip_runtime.h>
#include <math.h>

#define D 128
#define EPSV 1e-5f

typedef unsigned short ushort_t;
typedef unsigned char uchar_t;
typedef __attribute__((ext_vector_type(8))) short short8v;
typedef __attribute__((ext_vector_type(4))) float f32x4;
typedef __attribute__((ext_vector_type(2))) float f32x2;
typedef _Float16 half_t;
typedef __attribute__((ext_vector_type(2))) _Float16 h2;

#if __has_builtin(__builtin_amdgcn_cvt_pk_f16_fp8)
#define HAVE_F16P 1
#else
#define HAVE_F16P 0
#endif

// q is pre-scaled by (1/sqrt(32)) * log2(e) so the edge kernel uses exp2f directly
#define QKS (0.17677669529663687f * 1.4426950408889634f)

__device__ __forceinline__ float bf2f(unsigned u) {
    return __uint_as_float(u << 16);
}
__device__ __forceinline__ ushort_t f2bf(float f) {
    unsigned u = __float_as_uint(f);
    unsigned r = (u + 0x7fffu + ((u >> 16) & 1u)) >> 16;   // RNE
    return (ushort_t)r;
}
__device__ __forceinline__ float bfp(uint4 v, int i) {   // bf16 element i of 8
    unsigned w = (&v.x)[i >> 1];
    return bf2f((i & 1) ? (w >> 16) : (w & 0xffffu));
}

// q storage format: f16 when the fast fp8->f16 path exists, else bf16
__device__ __forceinline__ ushort_t qconv(float f) {
#if HAVE_F16P
    half_t h = (half_t)f;
    return __builtin_bit_cast(ushort_t, h);
#else
    return f2bf(f);
#endif
}

// unpack 8 fp8 (e4m3, 8 bytes in 2 uints) -> 8 f32 via HW cvt (fallback path)
#define UNPACK8_FP8(ux, uy, o) { \
    f32x2 _a = __builtin_amdgcn_cvt_pk_f32_fp8((int)(ux), false); \
    f32x2 _b = __builtin_amdgcn_cvt_pk_f32_fp8((int)(ux), true);  \
    f32x2 _c = __builtin_amdgcn_cvt_pk_f32_fp8((int)(uy), false); \
    f32x2 _d = __builtin_amdgcn_cvt_pk_f32_fp8((int)(uy), true);  \
    o[0] = _a.x; o[1] = _a.y; o[2] = _b.x; o[3] = _b.y;           \
    o[4] = _c.x; o[5] = _c.y; o[6] = _d.x; o[7] = _d.y; }

// pack 4 bf16 (in uints w0=[e1|e0], w1=[e3|e2]) -> 4 fp8 in one uint
__device__ __forceinline__ unsigned bf4_to_fp8x4(unsigned w0, unsigned w1) {
    int u = __builtin_amdgcn_cvt_pk_fp8_f32(bf2f(w0 & 0xffffu), bf2f(w0 >> 16), 0, false);
    u = __builtin_amdgcn_cvt_pk_fp8_f32(bf2f(w1 & 0xffffu), bf2f(w1 >> 16), u, true);
    return (unsigned)u;
}

__device__ __forceinline__ h2 h2_shfl_xor_add(h2 a, int off) {
    return a + __builtin_bit_cast(h2, __shfl_xor(__builtin_bit_cast(int, a), off));
}

// ========== merged: x -> bf16 (streaming) + degree count (same grid) ==========
__global__ void cvt_deg_kernel(const float* __restrict__ in, ushort_t* __restrict__ out, int n8,
                               const int* __restrict__ dst, int* __restrict__ deg, int E)
{
    int i = blockIdx.x * blockDim.x + threadIdx.x;
    if (i < n8) {
        float4 a = reinterpret_cast<const float4*>(in)[i * 2];
        float4 b = reinterpret_cast<const float4*>(in)[i * 2 + 1];
        uint4 o;
        o.x = (unsigned)f2bf(a.x) | ((unsigned)f2bf(a.y) << 16);
        o.y = (unsigned)f2bf(a.z) | ((unsigned)f2bf(a.w) << 16);
        o.z = (unsigned)f2bf(b.x) | ((unsigned)f2bf(b.y) << 16);
        o.w = (unsigned)f2bf(b.z) | ((unsigned)f2bf(b.w) << 16);
        reinterpret_cast<uint4*>(out)[i] = o;
    }
    if (i < E) atomicAdd(&deg[dst[i]], 1);
}

// ============ projection GEMM: pack/q/xr = xbf @ wt_all, one col-tile per block ============
// grid (MB, 5). pack row [384 B] fp8 = 16 groups of [k8|v8] (256 B) | xw*dinv (128 B).
__global__ __launch_bounds__(256)
void proj_gemm(const ushort_t* __restrict__ xbf,   // [M][128] bf16
               const ushort_t* __restrict__ Bt,    // wt_all [640][128]
               const float* __restrict__ bias,     // [640]
               const float* __restrict__ dinv,     // [M]
               uchar_t* __restrict__ pack, ushort_t* __restrict__ qb,
               ushort_t* __restrict__ xrb, int M)
{
    __shared__ ushort_t Cs[128 * 136];
    const int tid = threadIdx.x, lane = tid & 63, wid = tid >> 6;
    const int wr = wid >> 1, wc = wid & 1;
    const int R0 = blockIdx.x * 128;
    const int ct = blockIdx.y;

    short8v av[4][4];                         // [r][ks] bf16 A fragments
    #pragma unroll
    for (int r = 0; r < 4; ++r) {
        int gr = R0 + wr * 64 + r * 16 + (lane & 15);
        if (gr >= M) gr = M - 1;
        #pragma unroll
        for (int ks = 0; ks < 4; ++ks)
            av[r][ks] = *reinterpret_cast<const short8v*>(
                &xbf[(size_t)gr * 128 + ks * 32 + (lane >> 4) * 8]);
    }

    f32x4 acc[4][4] = {};
    #pragma unroll
    for (int ks = 0; ks < 4; ++ks) {
        short8v bv[4];
        #pragma unroll
        for (int c = 0; c < 4; ++c) {
            int col = ct * 128 + wc * 64 + c * 16 + (lane & 15);
            bv[c] = *reinterpret_cast<const short8v*>(
                &Bt[(size_t)col * 128 + ks * 32 + (lane >> 4) * 8]);
        }
        #pragma unroll
        for (int r = 0; r < 4; ++r)
            #pragma unroll
            for (int c = 0; c < 4; ++c)
                acc[r][c] = __builtin_amdgcn_mfma_f32_16x16x32_bf16(av[r][ks], bv[c], acc[r][c], 0, 0, 0);
    }

    #pragma unroll
    for (int r = 0; r < 4; ++r) {
        int rowb = wr * 64 + r * 16 + (lane >> 4) * 4;
        #pragma unroll
        for (int i = 0; i < 4; ++i) {
            float sc = 1.f;
            if (ct == 0) {
                int grow = R0 + rowb + i;
                if (grow >= M) grow = M - 1;
                sc = dinv[grow];              // pre-scale xw by dinv[src]
            }
            #pragma unroll
            for (int c = 0; c < 4; ++c) {
                int col = wc * 64 + c * 16 + (lane & 15);
                float val = acc[r][c][i] + bias[ct * 128 + col];
                if (ct == 0) val *= sc;
                if (ct == 1) val *= QKS;      // fold softmax scale + log2e into q
                Cs[(rowb + i) * 136 + col] = (ct == 1) ? qconv(val) : f2bf(val);
            }
        }
    }
    __syncthreads();

    if (ct == 1 || ct == 4) {                 // 16-bit outputs: q, x_r
        #pragma unroll
        for (int it = 0; it < 8; ++it) {      // 128 rows x 16 chunks of 16B
            int linear = tid + it * 256;
            int row = linear >> 4, ch = linear & 15;
            int gr = R0 + row;
            if (gr < M) {
                uint4 v = *reinterpret_cast<const uint4*>(&Cs[row * 136 + ch * 8]);
                ushort_t* dst = (ct == 1) ? (qb + (size_t)gr * 128)
                                          : (xrb + (size_t)gr * 128);
                *reinterpret_cast<uint4*>(dst + ch * 8) = v;
            }
        }
    } else {                                  // fp8 outputs: xw(ct0), k(ct2), v(ct3)
        #pragma unroll
        for (int it = 0; it < 4; ++it) {      // 128 rows x 8 chunks of 16 fp8
            int linear = tid + it * 256;
            int row = linear >> 3, ch = linear & 7;
            int gr = R0 + row;
            if (gr < M) {
                uint4 lo = *reinterpret_cast<const uint4*>(&Cs[row * 136 + ch * 16]);
                uint4 hi = *reinterpret_cast<const uint4*>(&Cs[row * 136 + ch * 16 + 8]);
                uint4 o;
                o.x = bf4_to_fp8x4(lo.x, lo.y);
                o.y = bf4_to_fp8x4(lo.z, lo.w);
                o.z = bf4_to_fp8x4(hi.x, hi.y);
                o.w = bf4_to_fp8x4(hi.z, hi.w);
                uchar_t* prow = pack + (size_t)gr * 384;
                if (ct == 0) {                // xw: contiguous at 256 + ch*16
                    *reinterpret_cast<uint4*>(prow + 256 + ch * 16) = o;
                } else if (ct == 2) {         // k: groups 2ch, 2ch+1, offset 0
                    *reinterpret_cast<uint2*>(prow + (2 * ch) * 16)     = make_uint2(o.x, o.y);
                    *reinterpret_cast<uint2*>(prow + (2 * ch + 1) * 16) = make_uint2(o.z, o.w);
                } else {                      // v: groups 2ch, 2ch+1, offset 8
                    *reinterpret_cast<uint2*>(prow + (2 * ch) * 16 + 8)     = make_uint2(o.x, o.y);
                    *reinterpret_cast<uint2*>(prow + (2 * ch + 1) * 16 + 8) = make_uint2(o.z, o.w);
                }
            }
        }
    }
}

// ============ fused FFN1 + FFN2 + residual + LayerNorm2 -> f32 out ============
__device__ __forceinline__ int swz(int ch, int row) {
    return (ch & 24) | ((ch ^ row) & 7);
}

__global__ __launch_bounds__(256)
void ffn_fused(const ushort_t* __restrict__ hlnb,     // [M][128] bf16
               const ushort_t* __restrict__ wt_rel,   // [256][128] bf16
               const ushort_t* __restrict__ wt_root,  // [128][256] bf16
               const float* __restrict__ g2, const float* __restrict__ b2,
               float* __restrict__ outf, int M)
{
    __shared__ float smem[128 * 130];                 // 66.6 KB
    ushort_t* Hs = (ushort_t*)smem;                   // hidden bf16 [128][256] swizzled
    const int tid = threadIdx.x, lane = tid & 63, wid = tid >> 6;
    const int wr = wid >> 1, wc = wid & 1;
    const int R0 = blockIdx.x * 128;

    short8v av[4][4];
    #pragma unroll
    for (int r = 0; r < 4; ++r) {
        int gr = R0 + wr * 64 + r * 16 + (lane & 15);
        if (gr >= M) gr = M - 1;
        #pragma unroll
        for (int ks = 0; ks < 4; ++ks)
            av[r][ks] = *reinterpret_cast<const short8v*>(
                &hlnb[(size_t)gr * 128 + ks * 32 + (lane >> 4) * 8]);
    }
    for (int ct = 0; ct < 2; ++ct) {
        f32x4 acc[4][4] = {};
        #pragma unroll
        for (int ks = 0; ks < 4; ++ks) {
            short8v bv[4];
            #pragma unroll
            for (int c = 0; c < 4; ++c) {
                int col = ct * 128 + wc * 64 + c * 16 + (lane & 15);
                bv[c] = *reinterpret_cast<const short8v*>(
                    &wt_rel[(size_t)col * 128 + ks * 32 + (lane >> 4) * 8]);
            }
            #pragma unroll
            for (int r = 0; r < 4; ++r)
                #pragma unroll
                for (int c = 0; c < 4; ++c)
                    acc[r][c] = __builtin_amdgcn_mfma_f32_16x16x32_bf16(av[r][ks], bv[c], acc[r][c], 0, 0, 0);
        }
        #pragma unroll
        for (int r = 0; r < 4; ++r) {
            int rowb = wr * 64 + r * 16 + (lane >> 4) * 4;
            #pragma unroll
            for (int i = 0; i < 4; ++i)
                #pragma unroll
                for (int c = 0; c < 4; ++c) {
                    int row = rowb + i;
                    int col = ct * 128 + wc * 64 + c * 16 + (lane & 15);
                    int ch = col >> 3, el = col & 7;
                    Hs[row * 256 + swz(ch, row) * 8 + el] = f2bf(fmaxf(acc[r][c][i], 0.f));
                }
        }
    }
    __syncthreads();

    f32x4 acc2[4][4] = {};
    #pragma unroll
    for (int ks = 0; ks < 8; ++ks) {
        short8v a2[4], bv[4];
        #pragma unroll
        for (int r = 0; r < 4; ++r) {
            int row = wr * 64 + r * 16 + (lane & 15);
            int ch = ks * 4 + (lane >> 4);
            a2[r] = *reinterpret_cast<const short8v*>(&Hs[row * 256 + swz(ch, row) * 8]);
        }
        #pragma unroll
        for (int c = 0; c < 4; ++c) {
            int col = wc * 64 + c * 16 + (lane & 15);
            bv[c] = *reinterpret_cast<const short8v*>(
                &wt_root[(size_t)col * 256 + ks * 32 + (lane >> 4) * 8]);
        }
        #pragma unroll
        for (int r = 0; r < 4; ++r)
            #pragma unroll
            for (int c = 0; c < 4; ++c)
                acc2[r][c] = __builtin_amdgcn_mfma_f32_16x16x32_bf16(a2[r], bv[c], acc2[r][c], 0, 0, 0);
    }
    __syncthreads();                          // hidden reads done; reuse as f32 C

    float* Cs = smem;                         // [128][130]
    #pragma unroll
    for (int r = 0; r < 4; ++r) {
        int rowb = wr * 64 + r * 16 + (lane >> 4) * 4;
        #pragma unroll
        for (int i = 0; i < 4; ++i)
            #pragma unroll
            for (int c = 0; c < 4; ++c)
                Cs[(rowb + i) * 130 + wc * 64 + c * 16 + (lane & 15)] = acc2[r][c][i];
    }
    __syncthreads();

    const float ga = g2[lane * 2], gb = g2[lane * 2 + 1];
    const float ba = b2[lane * 2], bb2 = b2[lane * 2 + 1];
    for (int rr = 0; rr < 32; ++rr) {
        int row = wid * 32 + rr;
        int gr = R0 + row;
        if (gr >= M) break;
        unsigned hu = *reinterpret_cast<const unsigned*>(&hlnb[(size_t)gr * 128 + lane * 2]);
        float t0 = Cs[row * 130 + lane * 2]     + bf2f(hu & 0xffffu);
        float t1 = Cs[row * 130 + lane * 2 + 1] + bf2f(hu >> 16);
        float ssum = t0 + t1;
        #pragma unroll
        for (int off = 1; off <= 32; off <<= 1) ssum += __shfl_xor(ssum, off);
        float mu = ssum * (1.f / 128.f);
        float dv0 = t0 - mu, dv1 = t1 - mu;
        float vsum = dv0 * dv0 + dv1 * dv1;
        #pragma unroll
        for (int off = 1; off <= 32; off <<= 1) vsum += __shfl_xor(vsum, off);
        float rs = rsqrtf(vsum * (1.f / 128.f) + EPSV);
        float2 o = make_float2(dv0 * rs * ga + ba, dv1 * rs * gb + bb2);
        *reinterpret_cast<float2*>(&outf[(size_t)gr * 128 + lane * 2]) = o;
    }
}

// =============== merged: scan1 (blocks < SB) + weight packing (blocks >= SB) ===============
__global__ __launch_bounds__(256)
void scan1_packw_kernel(const int* __restrict__ deg, int* __restrict__ row_start,
                        int* __restrict__ bsum, int n, int SB,
                        const float* __restrict__ wg, const float* __restrict__ wq,
                        const float* __restrict__ wk, const float* __restrict__ wv,
                        const float* __restrict__ wsk,
                        const float* __restrict__ bq, const float* __restrict__ bk,
                        const float* __restrict__ bv, const float* __restrict__ bsk,
                        const float* __restrict__ wrel, const float* __restrict__ wroot,
                        ushort_t* __restrict__ wt_all, ushort_t* __restrict__ wt_rel,
                        ushort_t* __restrict__ wt_root, float* __restrict__ bias_all)
{
    __shared__ int ws[4];
    if ((int)blockIdx.x < SB) {
        const int t = threadIdx.x, lane = t & 63, wid = t >> 6;
        const int base = blockIdx.x * 1024 + t * 4;
        int v0 = 0, v1 = 0, v2 = 0, v3 = 0;
        if (base + 3 < n) {
            int4 q = *reinterpret_cast<const int4*>(&deg[base]);
            v0 = q.x; v1 = q.y; v2 = q.z; v3 = q.w;
        } else {
            if (base < n)     v0 = deg[base];
            if (base + 1 < n) v1 = deg[base + 1];
            if (base + 2 < n) v2 = deg[base + 2];
            if (base + 3 < n) v3 = deg[base + 3];
        }
        int tot = v0 + v1 + v2 + v3;
        int inc = tot;
        #pragma unroll
        for (int off = 1; off < 64; off <<= 1) {
            int y = __shfl_up(inc, off);
            if (lane >= off) inc += y;
        }
        if (lane == 63) ws[wid] = inc;
        __syncthreads();
        int woff = 0;
        for (int w = 0; w < wid; ++w) woff += ws[w];
        int excl = woff + inc - tot;
        if (base < n)     row_start[base]     = excl;
        if (base + 1 < n) row_start[base + 1] = excl + v0;
        if (base + 2 < n) row_start[base + 2] = excl + v0 + v1;
        if (base + 3 < n) row_start[base + 3] = excl + v0 + v1 + v2;
        if (t == 0) bsum[blockIdx.x] = ws[0] + ws[1] + ws[2] + ws[3];
    } else {
        int i = (blockIdx.x - SB) * 256 + threadIdx.x;
        if (i < 640 * 128) {                         // wt_all[n][k] = W[k][n]
            int c = i >> 7, k = i & 127;
            const float* srcs[5] = {wg, wq, wk, wv, wsk};
            wt_all[i] = f2bf(srcs[c >> 7][k * 128 + (c & 127)]);
        } else if (i < 640 * 128 + 256 * 128) {
            int j = i - 640 * 128;
            int c = j >> 7, k = j & 127;
            wt_rel[j] = f2bf(wrel[k * 256 + c]);
        } else if (i < 640 * 128 + 256 * 128 + 128 * 256) {
            int j = i - (640 * 128 + 256 * 128);
            int c = j >> 8, k = j & 255;
            wt_root[j] = f2bf(wroot[k * 128 + c]);
        } else if (i < 640 * 128 + 256 * 128 + 128 * 256 + 640) {
            int c = i - (640 * 128 + 256 * 128 + 128 * 256);
            float b = 0.f;
            if (c >= 128) {
                const float* bs[4] = {bq, bk, bv, bsk};
                b = bs[(c - 128) >> 7][c & 127];
            }
            bias_all[c] = b;
        }
    }
}

// apply block offsets (prefix via parallel wave reduce); derive cursor, dinv, row_start[n]
__global__ __launch_bounds__(256)
void scan3_kernel(const int* __restrict__ deg, const int* __restrict__ bsum,
                  int* __restrict__ row_start, int* __restrict__ cursor,
                  float* __restrict__ dinv, int n, int E)
{
    __shared__ int boff_s;
    const int K = blockIdx.x >> 2;          // # of 1024-chunks before this block's chunk
    const int t = threadIdx.x;
    if (t < 64) {                           // parallel sum of bsum[0..K-1]
        int v = 0;
        for (int j = t; j < K; j += 64) v += bsum[j];
        #pragma unroll
        for (int off = 1; off <= 32; off <<= 1) v += __shfl_xor(v, off);
        if (t == 0) boff_s = v;
    }
    __syncthreads();
    int i = blockIdx.x * 256 + t;
    if (i < n) {
        int rs = row_start[i] + boff_s;
        row_start[i] = rs;
        cursor[i] = rs;
        int d = deg[i];
        dinv[i] = (d > 0) ? rsqrtf((float)d) : 0.f;
    }
    if (i == 0) row_start[n] = E;
}

__global__ void fill_kernel(const int* __restrict__ src, const int* __restrict__ dst,
                            int* __restrict__ cursor, int* __restrict__ csr_src, int E)
{
    int e = (blockIdx.x * blockDim.x + threadIdx.x) * 2;
    if (e + 1 < E) {
        int2 s2 = *reinterpret_cast<const int2*>(&src[e]);
        int2 d2 = *reinterpret_cast<const int2*>(&dst[e]);
        int p0 = atomicAdd(&cursor[d2.x], 1);
        csr_src[p0] = s2.x;
        int p1 = atomicAdd(&cursor[d2.y], 1);
        csr_src[p1] = s2.y;
    } else if (e < E) {
        int d = dst[e];
        int pos = atomicAdd(&cursor[d], 1);
        csr_src[pos] = src[e];
    }
}

// ===== fused: GCN gather + attention + beta gate + combine + LayerNorm1 =====
// pack row: 16 x [k8|v8] (256 B) | xw*dinv (128 B); row N zeroed. 4 edges/wave:
// slot = lane>>4, li = lane&15 (8 dims each). No online max (|alpha| << 1).
// q pre-scaled by QKS -> wgt = exp2f(p); inactive slots read zero-row (wgt=1, pad-corrected).
__global__ __launch_bounds__(256)
void edge_fused_kernel(const uchar_t* __restrict__ pack,
                       const ushort_t* __restrict__ qbf,
                       const ushort_t* __restrict__ xrbf,
                       const int* __restrict__ row_start,
                       const int* __restrict__ csr_src,
                       const float* __restrict__ dinv,
                       const float* __restrict__ b_gcn,
                       const float* __restrict__ w_beta,
                       const float* __restrict__ g1, const float* __restrict__ b1,
                       const float* __restrict__ local_w, const float* __restrict__ global_w,
                       ushort_t* __restrict__ hln_bf, int n)
{
    const int wid = threadIdx.x >> 6, lane = threadIdx.x & 63;
    const int node = blockIdx.x * 4 + wid;
    if (node >= n) return;
    const int slot = lane >> 4, li = lane & 15;
    const int d8 = li * 8;

    const int e0 = row_start[node], e1 = row_start[node + 1];
    const int cnt = e1 - e0;
    const float dn = dinv[node];

    float s = 0.f;
    float va[8], ga[8];

#if HAVE_F16P
    // ---- f16 packed-math path (q stored as f16, pre-scaled) ----
    uint4 qu = *reinterpret_cast<const uint4*>(&qbf[(size_t)node * 128 + d8]);
    h2 qh[4] = { __builtin_bit_cast(h2, qu.x), __builtin_bit_cast(h2, qu.y),
                 __builtin_bit_cast(h2, qu.z), __builtin_bit_cast(h2, qu.w) };
    h2 va2[4] = {}, ga2[4] = {};
    for (int j = e0; j < e1; j += 4) {
        const int je = j + slot;
        const int sidx = (je < e1) ? csr_src[je] : n;  // row n = zeros
        const uchar_t* prow = pack + (size_t)sidx * 384;
        uint4 kv = *reinterpret_cast<const uint4*>(prow + li * 16);       // k8|v8
        uint2 xu = *reinterpret_cast<const uint2*>(prow + 256 + li * 8);  // xw8
        h2 k0 = __builtin_amdgcn_cvt_pk_f16_fp8((short)(kv.x & 0xffffu));
        h2 k1 = __builtin_amdgcn_cvt_pk_f16_fp8((short)(kv.x >> 16));
        h2 k2 = __builtin_amdgcn_cvt_pk_f16_fp8((short)(kv.y & 0xffffu));
        h2 k3 = __builtin_amdgcn_cvt_pk_f16_fp8((short)(kv.y >> 16));
        float p = __builtin_amdgcn_fdot2(k0, qh[0], 0.f, false);
        p = __builtin_amdgcn_fdot2(k1, qh[1], p, false);
        p = __builtin_amdgcn_fdot2(k2, qh[2], p, false);
        p = __builtin_amdgcn_fdot2(k3, qh[3], p, false);
        p += __shfl_xor(p, 1);                        // head = li>>2 : 4-lane groups
        p += __shfl_xor(p, 2);
        float wgt = exp2f(p);                         // q pre-scaled; zero-row: exp2(0)=1
        s += wgt;
        half_t wh = (half_t)wgt;
        h2 w2 = { wh, wh };
        h2 v0 = __builtin_amdgcn_cvt_pk_f16_fp8((short)(kv.z & 0xffffu));
        h2 v1 = __builtin_amdgcn_cvt_pk_f16_fp8((short)(kv.z >> 16));
        h2 v2 = __builtin_amdgcn_cvt_pk_f16_fp8((short)(kv.w & 0xffffu));
        h2 v3 = __builtin_amdgcn_cvt_pk_f16_fp8((short)(kv.w >> 16));
        va2[0] += w2 * v0; va2[1] += w2 * v1; va2[2] += w2 * v2; va2[3] += w2 * v3;
        h2 x0 = __builtin_amdgcn_cvt_pk_f16_fp8((short)(xu.x & 0xffffu));
        h2 x1 = __builtin_amdgcn_cvt_pk_f16_fp8((short)(xu.x >> 16));
        h2 x2 = __builtin_amdgcn_cvt_pk_f16_fp8((short)(xu.y & 0xffffu));
        h2 x3 = __builtin_amdgcn_cvt_pk_f16_fp8((short)(xu.y >> 16));
        ga2[0] += x0; ga2[1] += x1; ga2[2] += x2; ga2[3] += x3;
    }
    // slot-combine in f16 (8 h2 regs x 2 stages = 16 shfl)
    #pragma unroll
    for (int off = 16; off <= 32; off <<= 1) {
        #pragma unroll
        for (int i = 0; i < 4; ++i) {
            va2[i] = h2_shfl_xor_add(va2[i], off);
            ga2[i] = h2_shfl_xor_add(ga2[i], off);
        }
    }
    #pragma unroll
    for (int i = 0; i < 4; ++i) {
        va[2 * i] = (float)va2[i][0]; va[2 * i + 1] = (float)va2[i][1];
        ga[2 * i] = (float)ga2[i][0]; ga[2 * i + 1] = (float)ga2[i][1];
    }
#else
    // ---- fallback f32 path (q stored as bf16, pre-scaled) ----
    uint4 qu = *reinterpret_cast<const uint4*>(&qbf[(size_t)node * 128 + d8]);
    float q[8];
    #pragma unroll
    for (int i = 0; i < 8; ++i) q[i] = bfp(qu, i);
    #pragma unroll
    for (int i = 0; i < 8; ++i) { va[i] = 0.f; ga[i] = 0.f; }
    for (int j = e0; j < e1; j += 4) {
        const int je = j + slot;
        const int sidx = (je < e1) ? csr_src[je] : n;
        const uchar_t* prow = pack + (size_t)sidx * 384;
        uint4 kv = *reinterpret_cast<const uint4*>(prow + li * 16);
        uint2 xu = *reinterpret_cast<const uint2*>(prow + 256 + li * 8);
        float kf[8], vf[8], xf[8];
        UNPACK8_FP8(kv.x, kv.y, kf);
        UNPACK8_FP8(kv.z, kv.w, vf);
        UNPACK8_FP8(xu.x, xu.y, xf);
        float p = 0.f;
        #pragma unroll
        for (int i = 0; i < 8; ++i) p = fmaf(q[i], kf[i], p);
        p += __shfl_xor(p, 1);
        p += __shfl_xor(p, 2);
        float wgt = exp2f(p);
        s += wgt;
        #pragma unroll
        for (int i = 0; i < 8; ++i) {
            va[i] = fmaf(wgt, vf[i], va[i]);
            ga[i] += xf[i];
        }
    }
    #pragma unroll
    for (int off = 16; off <= 32; off <<= 1) {
        #pragma unroll
        for (int i = 0; i < 8; ++i) {
            va[i] += __shfl_xor(va[i], off);
            ga[i] += __shfl_xor(ga[i], off);
        }
    }
#endif

    // s combine + pad correction (each inactive slot added exp2(0)=1 exactly once)
    s += __shfl_xor(s, 16);
    s += __shfl_xor(s, 32);
    if (cnt > 0) s -= (float)((4 - (cnt & 3)) & 3);
    const float denom = fmaxf(s, 1e-16f);        // per-head (head = li>>2)

    uint4 xru = *reinterpret_cast<const uint4*>(&xrbf[(size_t)node * 128 + d8]);
    float t[8];
    float part = 0.f;
    #pragma unroll
    for (int i = 0; i < 8; ++i) {
        float og = va[i] / denom;
        float xr = bfp(xru, i);
        float lo = dn * ga[i] + b_gcn[d8 + i];   // dn applied post-loop (xw pre-scaled)
        part += og * w_beta[d8 + i] + xr * w_beta[128 + d8 + i]
              + (og - xr) * w_beta[256 + d8 + i];
        t[i] = lo;
        va[i] = og; ga[i] = xr;                   // reuse regs: va=og, ga=xr
    }
    // 16-lane reductions (slot groups are exact duplicates)
    #pragma unroll
    for (int off = 1; off <= 8; off <<= 1) part += __shfl_xor(part, off);
    const float beta = 1.f / (1.f + __expf(-part));

    const float lw = local_w[0], gw = global_w[0];
    float ssum = 0.f;
    #pragma unroll
    for (int i = 0; i < 8; ++i) {
        float go = beta * ga[i] + (1.f - beta) * va[i];
        t[i] = 2.f * (lw * t[i] + gw * go);
        ssum += t[i];
    }
    #pragma unroll
    for (int off = 1; off <= 8; off <<= 1) ssum += __shfl_xor(ssum, off);
    const float mu = ssum * (1.f / 128.f);
    float vsum = 0.f;
    #pragma unroll
    for (int i = 0; i < 8; ++i) { float d = t[i] - mu; vsum += d * d; }
    #pragma unroll
    for (int off = 1; off <= 8; off <<= 1) vsum += __shfl_xor(vsum, off);
    const float rs = rsqrtf(vsum * (1.f / 128.f) + EPSV);

    if (slot == 0) {
        uint4 o;
        #pragma unroll
        for (int i = 0; i < 4; ++i) {
            float o0 = (t[2*i]   - mu) * rs * g1[d8 + 2*i]   + b1[d8 + 2*i];
            float o1 = (t[2*i+1] - mu) * rs * g1[d8 + 2*i+1] + b1[d8 + 2*i+1];
            (&o.x)[i] = (unsigned)f2bf(o0) | ((unsigned)f2bf(o1) << 16);
        }
        *reinterpret_cast<uint4*>(&hln_bf[(size_t)node * 128 + d8]) = o;
    }
}

// =================== launch ===================
extern "C" void kernel_launch(void* const* d_in, const int* in_sizes, int n_in,
                              void* d_out, int out_size, void* d_ws, size_t ws_size,
                              hipStream_t stream)
{
    const float* x      = (const float*)d_in[0];
    const int*   ei     = (const int*)d_in[1];
    const float* w_gcn  = (const float*)d_in[2];
    const float* b_gcn  = (const float*)d_in[3];
    const float* wq     = (const float*)d_in[4];
    const float* bq     = (const float*)d_in[5];
    const float* wk     = (const float*)d_in[6];
    const float* bk     = (const float*)d_in[7];
    const float* wv     = (const float*)d_in[8];
    const float* bv     = (const float*)d_in[9];
    const float* w_skip = (const float*)d_in[10];
    const float* b_skip = (const float*)d_in[11];
    const float* w_beta = (const float*)d_in[12];
    const float* g1     = (const float*)d_in[13];
    const float* b1     = (const float*)d_in[14];
    const float* g2     = (const float*)d_in[15];
    const float* b2     = (const float*)d_in[16];
    const float* w_rel  = (const float*)d_in[17];
    const float* w_root = (const float*)d_in[18];
    const float* lw     = (const float*)d_in[19];
    const float* gw     = (const float*)d_in[20];

    const int N = in_sizes[0] / D;
    const int E = in_sizes[1] / 2;
    const int* src = ei;
    const int* dst = ei + E;

    char* wsb = (char*)d_ws;
    size_t off = 0;
    auto alloc = [&](size_t bytes) -> void* {
        void* p = wsb + off;
        off += (bytes + 255) & ~(size_t)255;
        return p;
    };
    uchar_t*  pack_kvx = (uchar_t*)alloc((size_t)(N + 1) * 384);   // [k8|v8]x16 | xw fp8
    ushort_t* xbf      = (ushort_t*)alloc((size_t)N * 128 * 2);
    ushort_t* qb_bf    = (ushort_t*)alloc((size_t)N * 128 * 2);
    ushort_t* xr_bf    = (ushort_t*)alloc((size_t)N * 128 * 2);
    ushort_t* hln_bf   = (ushort_t*)alloc((size_t)N * 128 * 2);
    ushort_t* wt_all   = (ushort_t*)alloc(640 * 128 * 2);
    ushort_t* wt_rel   = (ushort_t*)alloc(256 * 128 * 2);
    ushort_t* wt_root  = (ushort_t*)alloc(128 * 256 * 2);
    float*    bias_all = (float*)alloc(640 * 4);
    int*      deg      = (int*)alloc((size_t)N * 4);
    int*      row_start= (int*)alloc((size_t)(N + 1) * 4);
    int*      cursor   = (int*)alloc((size_t)N * 4);
    int*      csr_src  = (int*)alloc((size_t)E * 4);
    float*    dinv     = (float*)alloc((size_t)N * 4);
    int*      bsum     = (int*)alloc(((size_t)(N + 1023) / 1024) * 4);

    float* out = (float*)d_out;
    const int SB = (N + 1023) / 1024;
    const int n8 = N * 16;                    // uint4 chunks for cvt

    // ---- graph prep (+ weight packing merged into scan1 launch) ----
    hipMemsetAsync(deg, 0, (size_t)N * sizeof(int), stream);
    hipMemsetAsync(pack_kvx + (size_t)N * 384, 0, 384, stream);    // zero dummy row
    {
        int work = (n8 > E) ? n8 : E;
        cvt_deg_kernel<<<dim3((work + 255) / 256), dim3(256), 0, stream>>>(
            x, xbf, n8, dst, deg, E);
    }
    scan1_packw_kernel<<<dim3(SB + 579), dim3(256), 0, stream>>>(
        deg, row_start, bsum, N, SB,
        w_gcn, wq, wk, wv, w_skip, bq, bk, bv, b_skip, w_rel, w_root,
        wt_all, wt_rel, wt_root, bias_all);
    scan3_kernel<<<dim3((N + 255) / 256), dim3(256), 0, stream>>>(
        deg, bsum, row_start, cursor, dinv, N, E);
    fill_kernel<<<dim3((E / 2 + 255) / 256), dim3(256), 0, stream>>>(src, dst, cursor, csr_src, E);

    // ---- fused projections: one col-tile per block, bf16 A ----
    const int MB = (N + 127) / 128;
    proj_gemm<<<dim3(MB, 5), dim3(256), 0, stream>>>(
        xbf, wt_all, bias_all, dinv, pack_kvx, qb_bf, xr_bf, N);

    // ---- fused edge phase (fp8 gathers, f16 packed math, exp2) ----
    edge_fused_kernel<<<dim3((N + 3) / 4), dim3(256), 0, stream>>>(
        pack_kvx, qb_bf, xr_bf, row_start, csr_src, dinv, b_gcn, w_beta,
        g1, b1, lw, gw, hln_bf, N);

    // ---- fused FFN + LN2 ----
    ffn_fused<<<dim3(MB), dim3(256), 0, stream>>>(
        hln_bf, wt_rel, wt_root, g2, b2, out, N);
}